// Round 15
// baseline (127.380 us; speedup 1.0000x reference)
//
#include <hip/hip_runtime.h>

#define BB 32
#define MM 512
#define NN 4096
#define KK 4
#define MLO 0.999998f         // 1 - 2^-19: kernA trigger margin, no false negatives
#define MARGF 0.999999f       // kernB ambiguity margin (approx err ~2e-7 << 1e-6)
#define TOLF 1e-6f            // kernB lq interval tolerance (relative)
#define FG_BITS 0x3F19999A    // bit pattern of 0.6f

// All IoU values are >= +0.0f, so float ordering == signed-int ordering on the
// bit patterns, with -1 (int) as a below-everything sentinel.

__device__ __forceinline__ int rfl(int x) {
    return __builtin_amdgcn_readfirstlane(x);
}
__device__ __forceinline__ float rflf(float x) {
    return __int_as_float(rfl(__float_as_int(x)));
}

__device__ __forceinline__ bool beatsI(int v1, int i1, int v2, int i2) {
    // total order: value descending, index ascending (JAX top_k tie-break)
    return (v1 > v2) || (v1 == v2 && i1 < i2);
}

// branchless compare-exchange keeping the winner in (av,ai)
#define CE(av, ai, bv, bi)                                        \
    {                                                             \
        bool _s = beatsI(bv, bi, av, ai);                         \
        int _mv = _s ? bv : av, _nv = _s ? av : bv;               \
        int _mi = _s ? bi : ai, _ni = _s ? ai : bi;               \
        av = _mv; bv = _nv; ai = _mi; bi = _ni;                   \
    }

struct T4 { int v0, v1, v2, v3; int i0, i1, i2, i3; float thr, c1, thrga; };

// ---------------------------------------------------------------------------
// Kernel A: per-gt top-4 (exact JAX top_k tie-break); writes pr_inds/gt_inds
// straight to d_out, topv + packed gt data {xyxy}, {area, gmx, gmx_tol} to
// ws, zeroes counts. 2 gts/wave, no LDS, L2-resident proposal stream.
// KEY (round-11 evidence, regressed when dropped in r12): top-4 state is
// readfirstlane'd to SGPRs -> the MERGE insert chain compiles to SALU
// (s_cmp/s_cselect), off the VALU pipe. r14 measured 63us without rfl vs
// ~49 with (r11); VALU instr/wave gap ~2.5k matches the insert machinery.
// ---------------------------------------------------------------------------
__global__ __launch_bounds__(256) void kernA(const float* __restrict__ gt,
                                             const float* __restrict__ pr,
                                             float* __restrict__ topv,
                                             float4* __restrict__ pack,
                                             int* __restrict__ counts,
                                             float* __restrict__ out) {
    const int b = blockIdx.x >> 6;         // 64 blocks per batch (512 gts / 8)
    const int mblk = blockIdx.x & 63;
    const int tid = threadIdx.x;
    const int wave = rfl(tid >> 6), lane = tid & 63;
    const int mbase = mblk * 8 + wave * 2; // 2 gts per wave
    const float4* g4 = (const float4*)(gt + (size_t)b * MM * 4);
    const float4* p4 = (const float4*)(pr + (size_t)b * NN * 4);

#define GTDEF(G) \
    float gx1_##G, gy1_##G, gx2_##G, gy2_##G, ga_##G; \
    { float4 gg = g4[mbase + G]; \
      float x1 = gg.x - 0.5f * gg.z, y1 = gg.y - 0.5f * gg.w; \
      float x2 = gg.x + 0.5f * gg.z, y2 = gg.y + 0.5f * gg.w; \
      gx1_##G = x1; gy1_##G = y1; gx2_##G = x2; gy2_##G = y2; \
      ga_##G = __fmul_rn(x2 - x1, y2 - y1); }

    GTDEF(0) GTDEF(1)

    T4 t0, t1;

    // ---- PRIME (j = 0): exact iou all lanes, butterfly -> uniform top-4 ----
#define PIOU(G, VB) \
    int VB; \
    { float ltx = fmaxf(gx1_##G, px1), lty = fmaxf(gy1_##G, py1); \
      float rbx = fminf(gx2_##G, px2), rby = fminf(gy2_##G, py2); \
      float wc = fmaxf(rbx - ltx, 0.0f), hc = fmaxf(rby - lty, 0.0f); \
      float inter = __fmul_rn(wc, hc); \
      float u = fmaxf((ga_##G + pa) - inter, 1e-9f); \
      VB = __float_as_int(inter / u); }

#define PRIME(T, VB, G) \
    { int x0 = VB, x1 = -1, x2 = -1, x3 = -1; \
      int y0 = lane, y1 = 0x7fffffff, y2 = 0x7fffffff, y3 = 0x7fffffff; \
      for (int off = 1; off < 64; off <<= 1) { \
        int b0 = __shfl_xor(x0, off), b1 = __shfl_xor(x1, off); \
        int b2 = __shfl_xor(x2, off), b3 = __shfl_xor(x3, off); \
        int j0 = __shfl_xor(y0, off), j1 = __shfl_xor(y1, off); \
        int j2 = __shfl_xor(y2, off), j3 = __shfl_xor(y3, off); \
        int z4 = b3, z5 = b2, z6 = b1, z7 = b0; \
        int w4 = j3, w5 = j2, w6 = j1, w7 = j0; \
        CE(x0, y0, z4, w4); CE(x1, y1, z5, w5); \
        CE(x2, y2, z6, w6); CE(x3, y3, z7, w7); \
        CE(x0, y0, x2, y2); CE(x1, y1, x3, y3); \
        CE(x0, y0, x1, y1); CE(x2, y2, x3, y3); \
      } \
      T.v0 = rfl(x0); T.v1 = rfl(x1); T.v2 = rfl(x2); T.v3 = rfl(x3); \
      T.i0 = rfl(y0); T.i1 = rfl(y1); T.i2 = rfl(y2); T.i3 = rfl(y3); \
      T.thr = (T.v3 <= 0) ? 0.0f : rflf(__int_as_float(T.v3) * MLO); \
      T.c1 = 1.0f + T.thr; T.thrga = T.thr * ga_##G; }

    {
        float4 qc = p4[lane];
        float px1 = qc.x - 0.5f * qc.z, py1 = qc.y - 0.5f * qc.w;
        float px2 = qc.x + 0.5f * qc.z, py2 = qc.y + 0.5f * qc.w;
        float pa = __fmul_rn(px2 - px1, py2 - py1);
        PIOU(0, vb0) PIOU(1, vb1)
        PRIME(t0, vb0, 0) PRIME(t1, vb1, 1)
    }

    // ---- STREAM (j = 1..63) ----
#define COMP(T, G, IN, TR) \
    float IN; bool TR; \
    { float ltx = fmaxf(gx1_##G, px1), lty = fmaxf(gy1_##G, py1); \
      float rbx = fminf(gx2_##G, px2), rby = fminf(gy2_##G, py2); \
      float wc = fmaxf(rbx - ltx, 0.0f), hc = fmaxf(rby - lty, 0.0f); \
      IN = __fmul_rn(wc, hc); \
      TR = IN * T.c1 > __fmaf_rn(T.thr, pa, T.thrga); }

    // Rare path: parallel exec-masked exact div; insert chain on SGPR state.
#define MERGE(T, G, MK, IN, TR) \
    if (MK) { \
      float iouv = 0.0f; \
      if (TR) { float uu = fmaxf((ga_##G + pa) - IN, 1e-9f); iouv = IN / uu; } \
      unsigned long long mk = MK; \
      do { \
        int l = __ffsll((unsigned long long)mk) - 1; mk &= mk - 1; \
        int vb = (int)__builtin_amdgcn_readlane(__float_as_int(iouv), l); \
        if (vb > T.v3) {                          /* strict: exact tie rule */ \
          int n = nb + l; \
          bool c2 = vb > T.v2, c1c = vb > T.v1, c0 = vb > T.v0; \
          T.v3 = c2 ? T.v2 : vb;                T.i3 = c2 ? T.i2 : n; \
          T.v2 = c2 ? (c1c ? T.v1 : vb) : T.v2; T.i2 = c2 ? (c1c ? T.i1 : n) : T.i2; \
          T.v1 = c1c ? (c0 ? T.v0 : vb) : T.v1; T.i1 = c1c ? (c0 ? T.i0 : n) : T.i1; \
          T.v0 = c0 ? vb : T.v0;                T.i0 = c0 ? n : T.i0; \
        } \
      } while (mk); \
      T.thr = (T.v3 == 0) ? 0.0f : rflf(__int_as_float(T.v3) * MLO); \
      T.c1 = 1.0f + T.thr; T.thrga = T.thr * ga_##G; \
    }

    float4 qn = p4[64 + lane];
    for (int j = 1; j < 64; ++j) {
        float4 qc = qn;
        int jn = (j < 63) ? j + 1 : 63;
        qn = p4[jn * 64 + lane];           // prefetch next tile (L2-resident)
        float px1 = qc.x - 0.5f * qc.z, py1 = qc.y - 0.5f * qc.w;
        float px2 = qc.x + 0.5f * qc.z, py2 = qc.y + 0.5f * qc.w;
        float pa = __fmul_rn(px2 - px1, py2 - py1);
        const int nb = j * 64;
        COMP(t0, 0, in0, tr0)
        COMP(t1, 1, in1, tr1)
        unsigned long long mk0 = __ballot(tr0), mk1 = __ballot(tr1);
        if (mk0 | mk1) {                   // single rare branch per iter
            MERGE(t0, 0, mk0, in0, tr0)
            MERGE(t1, 1, mk1, in1, tr1)
        }
    }

    if (lane == 0) {
        float* pi = out + (size_t)BB * MM * KK;
        float* gi = out + (size_t)2 * BB * MM * KK;
#define WOUT(T, G) \
        { int gm = b * MM + mbase + G; \
          float gmxf = __int_as_float(T.v0); \
          topv[gm * KK + 0] = gmxf; \
          topv[gm * KK + 1] = __int_as_float(T.v1); \
          topv[gm * KK + 2] = __int_as_float(T.v2); \
          topv[gm * KK + 3] = __int_as_float(T.v3); \
          pi[gm * KK + 0] = (float)T.i0; pi[gm * KK + 1] = (float)T.i1; \
          pi[gm * KK + 2] = (float)T.i2; pi[gm * KK + 3] = (float)T.i3; \
          float fm = (float)(mbase + G); \
          gi[gm * KK + 0] = fm; gi[gm * KK + 1] = fm; \
          gi[gm * KK + 2] = fm; gi[gm * KK + 3] = fm; \
          pack[gm * 2 + 0] = make_float4(gx1_##G, gy1_##G, gx2_##G, gy2_##G); \
          pack[gm * 2 + 1] = make_float4(ga_##G, gmxf, gmxf * TOLF, 0.0f); \
          counts[gm] = 0; }
        WOUT(t0, 0) WOUT(t1, 1)
    }
}

// ---------------------------------------------------------------------------
// Kernel B: per-proposal argmax over gts (first-max), fg/lq, count scatter.
// Round-8 geometry (64 proposals/block, 4-quarter split, grid 2048, LDS
// staged) + BRANCHLESS rcp-approx fast path (~27 ops/iter, NO div, NO
// branch -- r14's per-lane trigger branch was taken 97% of iters):
//   q = IN * v_rcp(u)   (rel err <~2e-7)
// tracks approx (q1,m1) best, q2 runner-up, lq interval candidates
// (|q-gmx| <= gmx*1e-6, 1 slot + count). Epilogue per thread: exact IEEE
// div for m1 (output value + fg test) and for the lq slot. Threads with
// q2 >= q1*MARGF (ambiguous argmax / rounded tie possible) or lqc>=2 with
// failed slot take a masked exact rescan (expected wave-any rate ~0.2%).
// Margins strictly dominate approx error -> results bit-identical to the
// reference. Quarter merge in m-order with strict > (first-max), as r8-r14.
// ---------------------------------------------------------------------------
__global__ __launch_bounds__(256) void kernB(const float* __restrict__ pr,
                                             const float4* __restrict__ pack,
                                             int* __restrict__ counts) {
    __shared__ float4 sG[MM];              // xyxy, 8 KB
    __shared__ float4 sA[MM];              // (ar, gmx, gmx_tol, 0), 8 KB
    __shared__ int sV[256], sI[256], sL[256];   // 3 KB
    const int b = blockIdx.x >> 6;         // 64 blocks per batch (4096/64)
    const int nblk = blockIdx.x & 63;
    const int tid = threadIdx.x;

    const float4* gp = pack + (size_t)b * MM * 2;
    for (int i = tid; i < MM; i += 256) {
        sG[i] = gp[i * 2];
        sA[i] = gp[i * 2 + 1];
    }

    const int lane = tid & 63;
    const int qtr = tid >> 6;
    const int m0 = qtr * 128;
    const int n = nblk * 64 + lane;
    float4 qq = ((const float4*)(pr + (size_t)b * NN * 4))[n];
    const float qx1 = qq.x - 0.5f * qq.z, qy1 = qq.y - 0.5f * qq.w;
    const float qx2 = qq.x + 0.5f * qq.z, qy2 = qq.y + 0.5f * qq.w;
    const float pa = __fmul_rn(qx2 - qx1, qy2 - qy1);
    __syncthreads();

    float q1 = 0.0f, q2 = 0.0f;            // approx best / runner-up
    int m1 = m0;
    int lqm = m0, lqc = 0;

    #pragma unroll 4
    for (int mm = 0; mm < 128; ++mm) {
        const int m = m0 + mm;
        float4 gb = sG[m];                 // broadcast ds_read_b128
        float4 ax = sA[m];                 // broadcast ds_read_b128
        float ltx = fmaxf(gb.x, qx1), lty = fmaxf(gb.y, qy1);
        float rbx = fminf(gb.z, qx2), rby = fminf(gb.w, qy2);
        float w = fmaxf(rbx - ltx, 0.0f), h = fmaxf(rby - lty, 0.0f);
        float IN = __fmul_rn(w, h);
        float u = fmaxf((ax.x + pa) - IN, 1e-9f);
        float q = IN * __frcp_rn(u);       // NOTE: maps to v_rcp+mul approx?
        // argmax approx with runner-up tracking
        bool c = q > q1;
        q2 = c ? q1 : fmaxf(q2, q);
        q1 = c ? q : q1;
        m1 = c ? m : m1;
        // lq interval candidate (gmx==0 -> tol 0 -> requires q==0 exactly)
        bool d = fabsf(q - ax.y) <= ax.z;
        lqm = d ? m : lqm;                 // keep last candidate
        lqc += d ? 1 : 0;
    }

    // exact best value (recompute m1 with exact IEEE div)
    float bestE;
    {
        float4 gb = sG[m1]; float4 ax = sA[m1];
        float ltx = fmaxf(gb.x, qx1), lty = fmaxf(gb.y, qy1);
        float rbx = fminf(gb.z, qx2), rby = fminf(gb.w, qy2);
        float w = fmaxf(rbx - ltx, 0.0f), h = fmaxf(rby - lty, 0.0f);
        float IN = __fmul_rn(w, h);
        float u = fmaxf((ax.x + pa) - IN, 1e-9f);
        bestE = IN / u;
    }
    // lq slot exact verification
    bool lqF;
    {
        float4 gb = sG[lqm]; float4 ax = sA[lqm];
        float ltx = fmaxf(gb.x, qx1), lty = fmaxf(gb.y, qy1);
        float rbx = fminf(gb.z, qx2), rby = fminf(gb.w, qy2);
        float w = fmaxf(rbx - ltx, 0.0f), h = fmaxf(rby - lty, 0.0f);
        float IN = __fmul_rn(w, h);
        float u = fmaxf((ax.x + pa) - IN, 1e-9f);
        lqF = (lqc > 0) && ((IN / u) == ax.y);
    }
    // rare exact rescan: ambiguous argmax or unresolved lq
    bool ambig = (q1 > 0.0f) && (q2 >= q1 * MARGF);
    bool need = ambig || (lqc >= 2 && !lqF);
    if (__ballot(need)) {
        if (need) {
            float bb = 0.0f; int bi = m0; bool ll = false;
            for (int mm = 0; mm < 128; ++mm) {
                const int m = m0 + mm;
                float4 gb = sG[m]; float4 ax = sA[m];
                float ltx = fmaxf(gb.x, qx1), lty = fmaxf(gb.y, qy1);
                float rbx = fminf(gb.z, qx2), rby = fminf(gb.w, qy2);
                float w = fmaxf(rbx - ltx, 0.0f), h = fmaxf(rby - lty, 0.0f);
                float IN = __fmul_rn(w, h);
                float u = fmaxf((ax.x + pa) - IN, 1e-9f);
                float iou = IN / u;        // exact IEEE everywhere
                bool c = iou > bb;         // first max kept, like jnp.argmax
                bb = c ? iou : bb;
                bi = c ? m : bi;
                ll = ll || (iou == ax.y);
            }
            bestE = bb; m1 = bi; lqF = ll;
        }
    }

    sV[tid] = __float_as_int(bestE);
    sI[tid] = m1;
    sL[tid] = lqF ? 1 : 0;
    __syncthreads();

    if (tid < 64) {
        int v = sV[tid], i = sI[tid], L = sL[tid];
        #pragma unroll
        for (int q_ = 1; q_ < 4; ++q_) {
            int v2 = sV[tid + q_ * 64], i2 = sI[tid + q_ * 64];
            L |= sL[tid + q_ * 64];
            bool c = v2 > v;               // strict: lower quarter wins ties
            v = c ? v2 : v;
            i = c ? i2 : i;
        }
        if (v >= FG_BITS || L) {           // int cmp == float cmp (non-neg)
            atomicAdd(&counts[b * MM + i], 1);
        }
    }
}

// ---------------------------------------------------------------------------
// Kernel C: write scores + valid sections (pr_inds/gt_inds done by kernA).
// ---------------------------------------------------------------------------
__global__ __launch_bounds__(256) void kernC(const float* __restrict__ topv,
                                             const int* __restrict__ counts,
                                             float* __restrict__ out) {
    const int gm = blockIdx.x * 256 + threadIdx.x;   // 0 .. B*M-1
    if (gm >= BB * MM) return;
    const int cnt = counts[gm];
    float* sc = out;
    float* va = out + (size_t)3 * BB * MM * KK;
    #pragma unroll
    for (int k = 0; k < KK; ++k) {
        const bool val = k < cnt;
        sc[gm * KK + k] = val ? topv[gm * KK + k] : 0.0f;
        va[gm * KK + k] = val ? 1.0f : 0.0f;
    }
}

extern "C" void kernel_launch(void* const* d_in, const int* in_sizes, int n_in,
                              void* d_out, int out_size, void* d_ws, size_t ws_size,
                              hipStream_t stream) {
    const float* gt = (const float*)d_in[0];   // [B,M,4] cxcywh
    const float* pr = (const float*)d_in[1];   // [B,N,4] cxcywh
    // d_in[2] (gt_labels) is unused by the reference outputs.
    float* out = (float*)d_out;
    char* ws = (char*)d_ws;

    int*    counts = (int*)(ws);                    //  64 KB @ 0
    float*  topv   = (float*)(ws + (1 << 16));      // 256 KB @ 64K
    float4* pack   = (float4*)(ws + (5 << 16));     // 512 KB @ 320K (tot 832K)

    kernA<<<BB * (MM / 8), 256, 0, stream>>>(gt, pr, topv, pack, counts, out);
    kernB<<<BB * (NN / 64), 256, 0, stream>>>(pr, pack, counts);
    kernC<<<(BB * MM + 255) / 256, 256, 0, stream>>>(topv, counts, out);
}

// Round 16
// 112.168 us; speedup vs baseline: 1.1356x; 1.1356x over previous
//
#include <hip/hip_runtime.h>

#define BB 32
#define MM 512
#define NN 4096
#define KK 4
#define MLO 0.999998f         // 1 - 2^-19: kernA trigger margin, no false negatives
#define CMG 0.9999995f        // 1 - 2^-21: close/lq margin, dominates all roundings
#define FG_BITS 0x3F19999A    // bit pattern of 0.6f

// All IoU values are >= +0.0f, so float ordering == signed-int ordering on the
// bit patterns, with -1 (int) as a below-everything sentinel.

__device__ __forceinline__ int rfl(int x) {
    return __builtin_amdgcn_readfirstlane(x);
}
__device__ __forceinline__ float rflf(float x) {
    return __int_as_float(rfl(__float_as_int(x)));
}

__device__ __forceinline__ bool beatsI(int v1, int i1, int v2, int i2) {
    // total order: value descending, index ascending (JAX top_k tie-break)
    return (v1 > v2) || (v1 == v2 && i1 < i2);
}

// branchless compare-exchange keeping the winner in (av,ai)
#define CE(av, ai, bv, bi)                                        \
    {                                                             \
        bool _s = beatsI(bv, bi, av, ai);                         \
        int _mv = _s ? bv : av, _nv = _s ? av : bv;               \
        int _mi = _s ? bi : ai, _ni = _s ? ai : bi;               \
        av = _mv; bv = _nv; ai = _mi; bi = _ni;                   \
    }

struct T4 { int v0, v1, v2, v3; int i0, i1, i2, i3; float thr, c1, thrga; };

// ---------------------------------------------------------------------------
// Kernel A (round-15 verbatim, ~40us measured): per-gt top-4 (exact JAX
// top_k tie-break); writes pr_inds/gt_inds straight to d_out, topv + packed
// gt data {xyxy}, {area, gmx, gmx*CMG} to ws, zeroes counts. 2 gts/wave, no
// LDS, L2-resident proposal stream. Top-4 state readfirstlane'd to SGPRs ->
// MERGE insert chain on SALU (r14 without rfl = 63us, r15 with = ~40us).
// ---------------------------------------------------------------------------
__global__ __launch_bounds__(256) void kernA(const float* __restrict__ gt,
                                             const float* __restrict__ pr,
                                             float* __restrict__ topv,
                                             float4* __restrict__ pack,
                                             int* __restrict__ counts,
                                             float* __restrict__ out) {
    const int b = blockIdx.x >> 6;         // 64 blocks per batch (512 gts / 8)
    const int mblk = blockIdx.x & 63;
    const int tid = threadIdx.x;
    const int wave = rfl(tid >> 6), lane = tid & 63;
    const int mbase = mblk * 8 + wave * 2; // 2 gts per wave
    const float4* g4 = (const float4*)(gt + (size_t)b * MM * 4);
    const float4* p4 = (const float4*)(pr + (size_t)b * NN * 4);

#define GTDEF(G) \
    float gx1_##G, gy1_##G, gx2_##G, gy2_##G, ga_##G; \
    { float4 gg = g4[mbase + G]; \
      float x1 = gg.x - 0.5f * gg.z, y1 = gg.y - 0.5f * gg.w; \
      float x2 = gg.x + 0.5f * gg.z, y2 = gg.y + 0.5f * gg.w; \
      gx1_##G = x1; gy1_##G = y1; gx2_##G = x2; gy2_##G = y2; \
      ga_##G = __fmul_rn(x2 - x1, y2 - y1); }

    GTDEF(0) GTDEF(1)

    T4 t0, t1;

    // ---- PRIME (j = 0): exact iou all lanes, butterfly -> uniform top-4 ----
#define PIOU(G, VB) \
    int VB; \
    { float ltx = fmaxf(gx1_##G, px1), lty = fmaxf(gy1_##G, py1); \
      float rbx = fminf(gx2_##G, px2), rby = fminf(gy2_##G, py2); \
      float wc = fmaxf(rbx - ltx, 0.0f), hc = fmaxf(rby - lty, 0.0f); \
      float inter = __fmul_rn(wc, hc); \
      float u = fmaxf((ga_##G + pa) - inter, 1e-9f); \
      VB = __float_as_int(inter / u); }

#define PRIME(T, VB, G) \
    { int x0 = VB, x1 = -1, x2 = -1, x3 = -1; \
      int y0 = lane, y1 = 0x7fffffff, y2 = 0x7fffffff, y3 = 0x7fffffff; \
      for (int off = 1; off < 64; off <<= 1) { \
        int b0 = __shfl_xor(x0, off), b1 = __shfl_xor(x1, off); \
        int b2 = __shfl_xor(x2, off), b3 = __shfl_xor(x3, off); \
        int j0 = __shfl_xor(y0, off), j1 = __shfl_xor(y1, off); \
        int j2 = __shfl_xor(y2, off), j3 = __shfl_xor(y3, off); \
        int z4 = b3, z5 = b2, z6 = b1, z7 = b0; \
        int w4 = j3, w5 = j2, w6 = j1, w7 = j0; \
        CE(x0, y0, z4, w4); CE(x1, y1, z5, w5); \
        CE(x2, y2, z6, w6); CE(x3, y3, z7, w7); \
        CE(x0, y0, x2, y2); CE(x1, y1, x3, y3); \
        CE(x0, y0, x1, y1); CE(x2, y2, x3, y3); \
      } \
      T.v0 = rfl(x0); T.v1 = rfl(x1); T.v2 = rfl(x2); T.v3 = rfl(x3); \
      T.i0 = rfl(y0); T.i1 = rfl(y1); T.i2 = rfl(y2); T.i3 = rfl(y3); \
      T.thr = (T.v3 <= 0) ? 0.0f : rflf(__int_as_float(T.v3) * MLO); \
      T.c1 = 1.0f + T.thr; T.thrga = T.thr * ga_##G; }

    {
        float4 qc = p4[lane];
        float px1 = qc.x - 0.5f * qc.z, py1 = qc.y - 0.5f * qc.w;
        float px2 = qc.x + 0.5f * qc.z, py2 = qc.y + 0.5f * qc.w;
        float pa = __fmul_rn(px2 - px1, py2 - py1);
        PIOU(0, vb0) PIOU(1, vb1)
        PRIME(t0, vb0, 0) PRIME(t1, vb1, 1)
    }

    // ---- STREAM (j = 1..63) ----
#define COMP(T, G, IN, TR) \
    float IN; bool TR; \
    { float ltx = fmaxf(gx1_##G, px1), lty = fmaxf(gy1_##G, py1); \
      float rbx = fminf(gx2_##G, px2), rby = fminf(gy2_##G, py2); \
      float wc = fmaxf(rbx - ltx, 0.0f), hc = fmaxf(rby - lty, 0.0f); \
      IN = __fmul_rn(wc, hc); \
      TR = IN * T.c1 > __fmaf_rn(T.thr, pa, T.thrga); }

    // Rare path: parallel exec-masked exact div; insert chain on SGPR state.
#define MERGE(T, G, MK, IN, TR) \
    if (MK) { \
      float iouv = 0.0f; \
      if (TR) { float uu = fmaxf((ga_##G + pa) - IN, 1e-9f); iouv = IN / uu; } \
      unsigned long long mk = MK; \
      do { \
        int l = __ffsll((unsigned long long)mk) - 1; mk &= mk - 1; \
        int vb = (int)__builtin_amdgcn_readlane(__float_as_int(iouv), l); \
        if (vb > T.v3) {                          /* strict: exact tie rule */ \
          int n = nb + l; \
          bool c2 = vb > T.v2, c1c = vb > T.v1, c0 = vb > T.v0; \
          T.v3 = c2 ? T.v2 : vb;                T.i3 = c2 ? T.i2 : n; \
          T.v2 = c2 ? (c1c ? T.v1 : vb) : T.v2; T.i2 = c2 ? (c1c ? T.i1 : n) : T.i2; \
          T.v1 = c1c ? (c0 ? T.v0 : vb) : T.v1; T.i1 = c1c ? (c0 ? T.i0 : n) : T.i1; \
          T.v0 = c0 ? vb : T.v0;                T.i0 = c0 ? n : T.i0; \
        } \
      } while (mk); \
      T.thr = (T.v3 == 0) ? 0.0f : rflf(__int_as_float(T.v3) * MLO); \
      T.c1 = 1.0f + T.thr; T.thrga = T.thr * ga_##G; \
    }

    float4 qn = p4[64 + lane];
    for (int j = 1; j < 64; ++j) {
        float4 qc = qn;
        int jn = (j < 63) ? j + 1 : 63;
        qn = p4[jn * 64 + lane];           // prefetch next tile (L2-resident)
        float px1 = qc.x - 0.5f * qc.z, py1 = qc.y - 0.5f * qc.w;
        float px2 = qc.x + 0.5f * qc.z, py2 = qc.y + 0.5f * qc.w;
        float pa = __fmul_rn(px2 - px1, py2 - py1);
        const int nb = j * 64;
        COMP(t0, 0, in0, tr0)
        COMP(t1, 1, in1, tr1)
        unsigned long long mk0 = __ballot(tr0), mk1 = __ballot(tr1);
        if (mk0 | mk1) {                   // single rare branch per iter
            MERGE(t0, 0, mk0, in0, tr0)
            MERGE(t1, 1, mk1, in1, tr1)
        }
    }

    if (lane == 0) {
        float* pi = out + (size_t)BB * MM * KK;
        float* gi = out + (size_t)2 * BB * MM * KK;
#define WOUT(T, G) \
        { int gm = b * MM + mbase + G; \
          float gmxf = __int_as_float(T.v0); \
          topv[gm * KK + 0] = gmxf; \
          topv[gm * KK + 1] = __int_as_float(T.v1); \
          topv[gm * KK + 2] = __int_as_float(T.v2); \
          topv[gm * KK + 3] = __int_as_float(T.v3); \
          pi[gm * KK + 0] = (float)T.i0; pi[gm * KK + 1] = (float)T.i1; \
          pi[gm * KK + 2] = (float)T.i2; pi[gm * KK + 3] = (float)T.i3; \
          float fm = (float)(mbase + G); \
          gi[gm * KK + 0] = fm; gi[gm * KK + 1] = fm; \
          gi[gm * KK + 2] = fm; gi[gm * KK + 3] = fm; \
          pack[gm * 2 + 0] = make_float4(gx1_##G, gy1_##G, gx2_##G, gy2_##G); \
          pack[gm * 2 + 1] = make_float4(ga_##G, gmxf, gmxf * CMG, 0.0f); \
          counts[gm] = 0; }
        WOUT(t0, 0) WOUT(t1, 1)
    }
}

// ---------------------------------------------------------------------------
// Kernel B: per-proposal argmax over gts (first-max), fg/lq, count scatter.
// R8 geometry (64 proposals/block, 4 quarters x 128 gts, LDS staged, grid
// 2048 -> 32 waves/CU) with a FRACTION-STATE cross-mult loop -- NO div, NO
// rcp in the hot loop (r15's __frcp_rn expanded to a div-cost sequence):
//   best kept as (INb, ub, mb); update iff IN*ub > INb*u (exact-max,
//   first-m on exact ties).
// Exactness vs reference (first-m of max ROUNDED value):
//   close = (t1 > t2*CMG) && (t2 > t1*CMG) accumulated -- fires for every
//   pair that could round equal (same-RN pairs within 2^-23; product
//   rounding 2^-24 each; CMG leaves 4x slack) -> rare exact rescan.
//   lq candidates: IN >= u*gmxM (gmxM = gmx*CMG, covers all achievers of
//   RN(IN/u)==gmx); last slot + count; slot verified with one exact div;
//   cnt>=2 with failed slot -> rescan. gmx==0 columns: all m candidate,
//   slot verifies 0==0 -> lq=1 (correct: all-zero column).
// Epilogue: 2 exact IEEE divs (winner value+fg, slot verify). Quarter merge
// in m-order with strict > on rounded values (first-max), as r8-r15.
// ---------------------------------------------------------------------------
__global__ __launch_bounds__(256) void kernB(const float* __restrict__ pr,
                                             const float4* __restrict__ pack,
                                             int* __restrict__ counts) {
    __shared__ float4 sG[MM];              // xyxy, 8 KB
    __shared__ float4 sA[MM];              // (ar, gmx, gmx*CMG, 0), 8 KB
    __shared__ int sV[256], sI[256], sL[256];   // 3 KB
    const int b = blockIdx.x >> 6;         // 64 blocks per batch (4096/64)
    const int nblk = blockIdx.x & 63;
    const int tid = threadIdx.x;

    const float4* gp = pack + (size_t)b * MM * 2;
    for (int i = tid; i < MM; i += 256) {
        sG[i] = gp[i * 2];
        sA[i] = gp[i * 2 + 1];
    }

    const int lane = tid & 63;
    const int qtr = tid >> 6;
    const int m0 = qtr * 128;
    const int n = nblk * 64 + lane;
    float4 qq = ((const float4*)(pr + (size_t)b * NN * 4))[n];
    const float qx1 = qq.x - 0.5f * qq.z, qy1 = qq.y - 0.5f * qq.w;
    const float qx2 = qq.x + 0.5f * qq.z, qy2 = qq.y + 0.5f * qq.w;
    const float pa = __fmul_rn(qx2 - qx1, qy2 - qy1);
    __syncthreads();

    // fraction state: (0/1) == iou 0; first positive IN updates (exact >).
    float INb = 0.0f, ub = 1.0f;
    int mb = m0;
    bool closeacc = false;
    int ms = m0, cnt = 0;

    #pragma unroll 4
    for (int mm = 0; mm < 128; ++mm) {
        const int m = m0 + mm;
        float4 gb = sG[m];                 // broadcast ds_read_b128
        float4 ax = sA[m];                 // broadcast ds_read_b128
        float ltx = fmaxf(gb.x, qx1), lty = fmaxf(gb.y, qy1);
        float rbx = fminf(gb.z, qx2), rby = fminf(gb.w, qy2);
        float w = fmaxf(rbx - ltx, 0.0f), h = fmaxf(rby - lty, 0.0f);
        float IN = __fmul_rn(w, h);
        float u = fmaxf((ax.x + pa) - IN, 1e-9f);
        float t1 = __fmul_rn(IN, ub);
        float t2 = __fmul_rn(INb, u);
        bool c = t1 > t2;                  // exact-max, first-m on ties
        closeacc = closeacc || ((t1 > t2 * CMG) && (t2 > t1 * CMG));
        INb = c ? IN : INb;
        ub = c ? u : ub;
        mb = c ? m : mb;
        bool cd = IN >= __fmul_rn(u, ax.z);    // lq candidate interval
        ms = cd ? m : ms;
        cnt += cd ? 1 : 0;
    }

    // winner exact value (reference rounding)
    float bestE;
    {
        float4 gb = sG[mb]; float4 ax = sA[mb];
        float ltx = fmaxf(gb.x, qx1), lty = fmaxf(gb.y, qy1);
        float rbx = fminf(gb.z, qx2), rby = fminf(gb.w, qy2);
        float w = fmaxf(rbx - ltx, 0.0f), h = fmaxf(rby - lty, 0.0f);
        float IN = __fmul_rn(w, h);
        float u = fmaxf((ax.x + pa) - IN, 1e-9f);
        bestE = IN / u;
    }
    // lq slot verify (exact)
    bool lqF;
    {
        float4 gb = sG[ms]; float4 ax = sA[ms];
        float ltx = fmaxf(gb.x, qx1), lty = fmaxf(gb.y, qy1);
        float rbx = fminf(gb.z, qx2), rby = fminf(gb.w, qy2);
        float w = fmaxf(rbx - ltx, 0.0f), h = fmaxf(rby - lty, 0.0f);
        float IN = __fmul_rn(w, h);
        float u = fmaxf((ax.x + pa) - IN, 1e-9f);
        lqF = (cnt > 0) && ((IN / u) == ax.y);
    }
    // rare exact rescan: possible rounded tie at max, or unresolved lq
    bool need = closeacc || ((cnt >= 2) && !lqF);
    if (__ballot(need) != 0ull) {
        if (need) {
            float bb = 0.0f; int bi = m0; bool ll = false;
            for (int mm = 0; mm < 128; ++mm) {
                const int m = m0 + mm;
                float4 gb = sG[m]; float4 ax = sA[m];
                float ltx = fmaxf(gb.x, qx1), lty = fmaxf(gb.y, qy1);
                float rbx = fminf(gb.z, qx2), rby = fminf(gb.w, qy2);
                float w = fmaxf(rbx - ltx, 0.0f), h = fmaxf(rby - lty, 0.0f);
                float IN = __fmul_rn(w, h);
                float u = fmaxf((ax.x + pa) - IN, 1e-9f);
                float iou = IN / u;        // exact IEEE everywhere
                bool c = iou > bb;         // first max kept, like jnp.argmax
                bb = c ? iou : bb;
                bi = c ? m : bi;
                ll = ll || (iou == ax.y);
            }
            bestE = bb; mb = bi; lqF = ll;
        }
    }

    sV[tid] = __float_as_int(bestE);
    sI[tid] = mb;
    sL[tid] = lqF ? 1 : 0;
    __syncthreads();

    if (tid < 64) {
        int v = sV[tid], i = sI[tid], L = sL[tid];
        #pragma unroll
        for (int q_ = 1; q_ < 4; ++q_) {
            int v2 = sV[tid + q_ * 64], i2 = sI[tid + q_ * 64];
            L |= sL[tid + q_ * 64];
            bool c = v2 > v;               // strict: lower quarter wins ties
            v = c ? v2 : v;
            i = c ? i2 : i;
        }
        if (v >= FG_BITS || L) {           // int cmp == float cmp (non-neg)
            atomicAdd(&counts[b * MM + i], 1);
        }
    }
}

// ---------------------------------------------------------------------------
// Kernel C: write scores + valid sections (pr_inds/gt_inds done by kernA).
// ---------------------------------------------------------------------------
__global__ __launch_bounds__(256) void kernC(const float* __restrict__ topv,
                                             const int* __restrict__ counts,
                                             float* __restrict__ out) {
    const int gm = blockIdx.x * 256 + threadIdx.x;   // 0 .. B*M-1
    if (gm >= BB * MM) return;
    const int cnt = counts[gm];
    float* sc = out;
    float* va = out + (size_t)3 * BB * MM * KK;
    #pragma unroll
    for (int k = 0; k < KK; ++k) {
        const bool val = k < cnt;
        sc[gm * KK + k] = val ? topv[gm * KK + k] : 0.0f;
        va[gm * KK + k] = val ? 1.0f : 0.0f;
    }
}

extern "C" void kernel_launch(void* const* d_in, const int* in_sizes, int n_in,
                              void* d_out, int out_size, void* d_ws, size_t ws_size,
                              hipStream_t stream) {
    const float* gt = (const float*)d_in[0];   // [B,M,4] cxcywh
    const float* pr = (const float*)d_in[1];   // [B,N,4] cxcywh
    // d_in[2] (gt_labels) is unused by the reference outputs.
    float* out = (float*)d_out;
    char* ws = (char*)d_ws;

    int*    counts = (int*)(ws);                    //  64 KB @ 0
    float*  topv   = (float*)(ws + (1 << 16));      // 256 KB @ 64K
    float4* pack   = (float4*)(ws + (5 << 16));     // 512 KB @ 320K (tot 832K)

    kernA<<<BB * (MM / 8), 256, 0, stream>>>(gt, pr, topv, pack, counts, out);
    kernB<<<BB * (NN / 64), 256, 0, stream>>>(pr, pack, counts);
    kernC<<<(BB * MM + 255) / 256, 256, 0, stream>>>(topv, counts, out);
}

// Round 17
// 94.756 us; speedup vs baseline: 1.3443x; 1.1838x over previous
//
#include <hip/hip_runtime.h>

#define BB 32
#define MM 512
#define NN 4096
#define KK 4
#define MLO 0.999998f         // 1 - 2^-19: kernA trigger margin, no false negatives
#define CMG 0.9999995f        // 1 - 2^-21: close margin, dominates all roundings
#define FG_BITS 0x3F19999A    // bit pattern of 0.6f
#define NA_BLOCKS (BB * (MM / 8))   // 2048 A-role blocks

// All IoU values are >= +0.0f, so float ordering == signed-int ordering on the
// bit patterns, with -1 (int) as a below-everything sentinel.

__device__ __forceinline__ int rfl(int x) {
    return __builtin_amdgcn_readfirstlane(x);
}
__device__ __forceinline__ float rflf(float x) {
    return __int_as_float(rfl(__float_as_int(x)));
}

__device__ __forceinline__ bool beatsI(int v1, int i1, int v2, int i2) {
    return (v1 > v2) || (v1 == v2 && i1 < i2);
}

#define CE(av, ai, bv, bi)                                        \
    {                                                             \
        bool _s = beatsI(bv, bi, av, ai);                         \
        int _mv = _s ? bv : av, _nv = _s ? av : bv;               \
        int _mi = _s ? bi : ai, _ni = _s ? ai : bi;               \
        av = _mv; bv = _nv; ai = _mi; bi = _ni;                   \
    }

struct T4 { int v0, v1, v2, v3; int i0, i1, i2, i3; float thr, c1, thrga; };

// ---------------------------------------------------------------------------
// Fused kernel: blocks [0, 2048) run the A-role (per-gt top-4, r16-validated
// structure: 2 gts/wave, SGPR state, sparse trigger, masked-div MERGE);
// blocks [2048, 4096) run the B-role (per-proposal argmax, cross-mult
// fraction state + close detector, NO lq tracking, NO div in loop).
// B-role is now INDEPENDENT of A-role (stages raw gt itself), so both
// populations run concurrently -- fills B's 22% idle issue slots (r16:
// VALUBusy 78% @ occupancy 41%). lq moved to kernD (from A's top-4 ties).
// ---------------------------------------------------------------------------
__global__ __launch_bounds__(256) void kernAB(const float* __restrict__ gt,
                                              const float* __restrict__ pr,
                                              float* __restrict__ topv,
                                              int* __restrict__ topi,
                                              int* __restrict__ counts,
                                              int* __restrict__ bestv,
                                              int* __restrict__ bidxA,
                                              unsigned char* __restrict__ lqflag,
                                              int* __restrict__ allLq,
                                              float* __restrict__ out) {
    __shared__ float4 sG[MM];              // B-role: xyxy, 8 KB
    __shared__ float sAr[MM];              // B-role: area, 2 KB
    __shared__ int sV[256], sI[256];       // B-role reduce, 2 KB

    if (blockIdx.x < NA_BLOCKS) {
        // =================== A-role (r16 kernA, minus pack) ===================
        const int b = blockIdx.x >> 6;
        const int mblk = blockIdx.x & 63;
        const int tid = threadIdx.x;
        const int wave = rfl(tid >> 6), lane = tid & 63;
        const int mbase = mblk * 8 + wave * 2;
        const float4* g4 = (const float4*)(gt + (size_t)b * MM * 4);
        const float4* p4 = (const float4*)(pr + (size_t)b * NN * 4);

#define GTDEF(G) \
    float gx1_##G, gy1_##G, gx2_##G, gy2_##G, ga_##G; \
    { float4 gg = g4[mbase + G]; \
      float x1 = gg.x - 0.5f * gg.z, y1 = gg.y - 0.5f * gg.w; \
      float x2 = gg.x + 0.5f * gg.z, y2 = gg.y + 0.5f * gg.w; \
      gx1_##G = x1; gy1_##G = y1; gx2_##G = x2; gy2_##G = y2; \
      ga_##G = __fmul_rn(x2 - x1, y2 - y1); }

        GTDEF(0) GTDEF(1)

        T4 t0, t1;

#define PIOU(G, VB) \
    int VB; \
    { float ltx = fmaxf(gx1_##G, px1), lty = fmaxf(gy1_##G, py1); \
      float rbx = fminf(gx2_##G, px2), rby = fminf(gy2_##G, py2); \
      float wc = fmaxf(rbx - ltx, 0.0f), hc = fmaxf(rby - lty, 0.0f); \
      float inter = __fmul_rn(wc, hc); \
      float u = fmaxf((ga_##G + pa) - inter, 1e-9f); \
      VB = __float_as_int(inter / u); }

#define PRIME(T, VB, G) \
    { int x0 = VB, x1 = -1, x2 = -1, x3 = -1; \
      int y0 = lane, y1 = 0x7fffffff, y2 = 0x7fffffff, y3 = 0x7fffffff; \
      for (int off = 1; off < 64; off <<= 1) { \
        int b0 = __shfl_xor(x0, off), b1 = __shfl_xor(x1, off); \
        int b2 = __shfl_xor(x2, off), b3 = __shfl_xor(x3, off); \
        int j0 = __shfl_xor(y0, off), j1 = __shfl_xor(y1, off); \
        int j2 = __shfl_xor(y2, off), j3 = __shfl_xor(y3, off); \
        int z4 = b3, z5 = b2, z6 = b1, z7 = b0; \
        int w4 = j3, w5 = j2, w6 = j1, w7 = j0; \
        CE(x0, y0, z4, w4); CE(x1, y1, z5, w5); \
        CE(x2, y2, z6, w6); CE(x3, y3, z7, w7); \
        CE(x0, y0, x2, y2); CE(x1, y1, x3, y3); \
        CE(x0, y0, x1, y1); CE(x2, y2, x3, y3); \
      } \
      T.v0 = rfl(x0); T.v1 = rfl(x1); T.v2 = rfl(x2); T.v3 = rfl(x3); \
      T.i0 = rfl(y0); T.i1 = rfl(y1); T.i2 = rfl(y2); T.i3 = rfl(y3); \
      T.thr = (T.v3 <= 0) ? 0.0f : rflf(__int_as_float(T.v3) * MLO); \
      T.c1 = 1.0f + T.thr; T.thrga = T.thr * ga_##G; }

        {
            float4 qc = p4[lane];
            float px1 = qc.x - 0.5f * qc.z, py1 = qc.y - 0.5f * qc.w;
            float px2 = qc.x + 0.5f * qc.z, py2 = qc.y + 0.5f * qc.w;
            float pa = __fmul_rn(px2 - px1, py2 - py1);
            PIOU(0, vb0) PIOU(1, vb1)
            PRIME(t0, vb0, 0) PRIME(t1, vb1, 1)
        }

#define COMP(T, G, IN, TR) \
    float IN; bool TR; \
    { float ltx = fmaxf(gx1_##G, px1), lty = fmaxf(gy1_##G, py1); \
      float rbx = fminf(gx2_##G, px2), rby = fminf(gy2_##G, py2); \
      float wc = fmaxf(rbx - ltx, 0.0f), hc = fmaxf(rby - lty, 0.0f); \
      IN = __fmul_rn(wc, hc); \
      TR = IN * T.c1 > __fmaf_rn(T.thr, pa, T.thrga); }

#define MERGE(T, G, MK, IN, TR) \
    if (MK) { \
      float iouv = 0.0f; \
      if (TR) { float uu = fmaxf((ga_##G + pa) - IN, 1e-9f); iouv = IN / uu; } \
      unsigned long long mk = MK; \
      do { \
        int l = __ffsll((unsigned long long)mk) - 1; mk &= mk - 1; \
        int vb = (int)__builtin_amdgcn_readlane(__float_as_int(iouv), l); \
        if (vb > T.v3) { \
          int n = nb + l; \
          bool c2 = vb > T.v2, c1c = vb > T.v1, c0 = vb > T.v0; \
          T.v3 = c2 ? T.v2 : vb;                T.i3 = c2 ? T.i2 : n; \
          T.v2 = c2 ? (c1c ? T.v1 : vb) : T.v2; T.i2 = c2 ? (c1c ? T.i1 : n) : T.i2; \
          T.v1 = c1c ? (c0 ? T.v0 : vb) : T.v1; T.i1 = c1c ? (c0 ? T.i0 : n) : T.i1; \
          T.v0 = c0 ? vb : T.v0;                T.i0 = c0 ? n : T.i0; \
        } \
      } while (mk); \
      T.thr = (T.v3 == 0) ? 0.0f : rflf(__int_as_float(T.v3) * MLO); \
      T.c1 = 1.0f + T.thr; T.thrga = T.thr * ga_##G; \
    }

        float4 qn = p4[64 + lane];
        for (int j = 1; j < 64; ++j) {
            float4 qc = qn;
            int jn = (j < 63) ? j + 1 : 63;
            qn = p4[jn * 64 + lane];
            float px1 = qc.x - 0.5f * qc.z, py1 = qc.y - 0.5f * qc.w;
            float px2 = qc.x + 0.5f * qc.z, py2 = qc.y + 0.5f * qc.w;
            float pa = __fmul_rn(px2 - px1, py2 - py1);
            const int nb = j * 64;
            COMP(t0, 0, in0, tr0)
            COMP(t1, 1, in1, tr1)
            unsigned long long mk0 = __ballot(tr0), mk1 = __ballot(tr1);
            if (mk0 | mk1) {
                MERGE(t0, 0, mk0, in0, tr0)
                MERGE(t1, 1, mk1, in1, tr1)
            }
        }

        if (lane == 0) {
            float* pi = out + (size_t)BB * MM * KK;
            float* gi = out + (size_t)2 * BB * MM * KK;
#define WOUT(T, G) \
            { int gm = b * MM + mbase + G; \
              topv[gm * KK + 0] = __int_as_float(T.v0); \
              topv[gm * KK + 1] = __int_as_float(T.v1); \
              topv[gm * KK + 2] = __int_as_float(T.v2); \
              topv[gm * KK + 3] = __int_as_float(T.v3); \
              topi[gm * KK + 0] = T.i0; topi[gm * KK + 1] = T.i1; \
              topi[gm * KK + 2] = T.i2; topi[gm * KK + 3] = T.i3; \
              pi[gm * KK + 0] = (float)T.i0; pi[gm * KK + 1] = (float)T.i1; \
              pi[gm * KK + 2] = (float)T.i2; pi[gm * KK + 3] = (float)T.i3; \
              float fm = (float)(mbase + G); \
              gi[gm * KK + 0] = fm; gi[gm * KK + 1] = fm; \
              gi[gm * KK + 2] = fm; gi[gm * KK + 3] = fm; \
              counts[gm] = 0; }
            WOUT(t0, 0) WOUT(t1, 1)
        }
    } else {
        // =================== B-role (argmax only, no lq) ===================
        const int bid = blockIdx.x - NA_BLOCKS;
        const int b = bid >> 6;            // 64 blocks per batch (4096/64)
        const int nblk = bid & 63;
        const int tid = threadIdx.x;
        const float4* g4 = (const float4*)(gt + (size_t)b * MM * 4);

        for (int i = tid; i < MM; i += 256) {
            float4 gg = g4[i];
            float x1 = gg.x - 0.5f * gg.z, y1 = gg.y - 0.5f * gg.w;
            float x2 = gg.x + 0.5f * gg.z, y2 = gg.y + 0.5f * gg.w;
            sG[i] = make_float4(x1, y1, x2, y2);
            sAr[i] = __fmul_rn(x2 - x1, y2 - y1);
        }
        if (tid < 64) lqflag[(size_t)b * NN + nblk * 64 + tid] = 0;
        if (tid == 0 && nblk == 0) allLq[b] = 0;

        const int lane = tid & 63;
        const int qtr = tid >> 6;
        const int m0 = qtr * 128;
        const int n = nblk * 64 + lane;
        float4 qq = ((const float4*)(pr + (size_t)b * NN * 4))[n];
        const float qx1 = qq.x - 0.5f * qq.z, qy1 = qq.y - 0.5f * qq.w;
        const float qx2 = qq.x + 0.5f * qq.z, qy2 = qq.y + 0.5f * qq.w;
        const float pa = __fmul_rn(qx2 - qx1, qy2 - qy1);
        __syncthreads();

        // fraction state (0/1) == iou 0 at m0; exact-> update, first-m ties.
        float INb = 0.0f, ub = 1.0f;
        int mb = m0;
        bool closeacc = false;

        #pragma unroll 4
        for (int mm = 0; mm < 128; ++mm) {
            const int m = m0 + mm;
            float4 gb = sG[m];
            float ar = sAr[m];
            float ltx = fmaxf(gb.x, qx1), lty = fmaxf(gb.y, qy1);
            float rbx = fminf(gb.z, qx2), rby = fminf(gb.w, qy2);
            float w = fmaxf(rbx - ltx, 0.0f), h = fmaxf(rby - lty, 0.0f);
            float IN = __fmul_rn(w, h);
            float u = fmaxf((ar + pa) - IN, 1e-9f);
            float t1 = __fmul_rn(IN, ub);
            float t2 = __fmul_rn(INb, u);
            bool c = t1 > t2;
            closeacc = closeacc || ((t1 > t2 * CMG) && (t2 > t1 * CMG));
            INb = c ? IN : INb;
            ub = c ? u : ub;
            mb = c ? m : mb;
        }

        float bestE;                        // winner exact rounded value
        {
            float4 gb = sG[mb];
            float ltx = fmaxf(gb.x, qx1), lty = fmaxf(gb.y, qy1);
            float rbx = fminf(gb.z, qx2), rby = fminf(gb.w, qy2);
            float w = fmaxf(rbx - ltx, 0.0f), h = fmaxf(rby - lty, 0.0f);
            float IN = __fmul_rn(w, h);
            float u = fmaxf((sAr[mb] + pa) - IN, 1e-9f);
            bestE = IN / u;
        }
        if (__ballot(closeacc) != 0ull) {   // rare rounded-tie rescan
            if (closeacc) {
                float bb = 0.0f; int bi = m0;
                for (int mm = 0; mm < 128; ++mm) {
                    const int m = m0 + mm;
                    float4 gb = sG[m];
                    float ltx = fmaxf(gb.x, qx1), lty = fmaxf(gb.y, qy1);
                    float rbx = fminf(gb.z, qx2), rby = fminf(gb.w, qy2);
                    float w = fmaxf(rbx - ltx, 0.0f), h = fmaxf(rby - lty, 0.0f);
                    float IN = __fmul_rn(w, h);
                    float u = fmaxf((sAr[m] + pa) - IN, 1e-9f);
                    float iou = IN / u;
                    bool c = iou > bb;      // first max of rounded values
                    bb = c ? iou : bb;
                    bi = c ? m : bi;
                }
                bestE = bb; mb = bi;
            }
        }

        sV[tid] = __float_as_int(bestE);
        sI[tid] = mb;
        __syncthreads();

        if (tid < 64) {
            int v = sV[tid], i = sI[tid];
            #pragma unroll
            for (int q_ = 1; q_ < 4; ++q_) {
                int v2 = sV[tid + q_ * 64], i2 = sI[tid + q_ * 64];
                bool c = v2 > v;           // strict: lower quarter wins ties
                v = c ? v2 : v;
                i = c ? i2 : i;
            }
            const size_t pidx = (size_t)b * NN + nblk * 64 + tid;
            bestv[pidx] = v;
            bidxA[pidx] = i;
        }
    }
}

// ---------------------------------------------------------------------------
// Kernel D: per-gt lq marking from top-4 ties (exact, no epsilon).
// Achievers of gt m's rounded max v0 are exactly {n : iou==v0}; top_k (value
// desc, idx asc) places all of them first, so v3<v0 -> achievers in {i0..i3}
// read off by float equality. Fallbacks (exact, ~never taken): v0==0 -> all
// proposals lq (per-batch flag); v3==v0 -> serial row rescan.
// ---------------------------------------------------------------------------
__global__ __launch_bounds__(256) void kernD(const float* __restrict__ topv,
                                             const int* __restrict__ topi,
                                             const float* __restrict__ gt,
                                             const float* __restrict__ pr,
                                             unsigned char* __restrict__ lqflag,
                                             int* __restrict__ allLq) {
    const int gm = blockIdx.x * 256 + threadIdx.x;   // 0 .. B*M-1
    if (gm >= BB * MM) return;
    const int b = gm >> 9, m = gm & (MM - 1);
    const float v0 = topv[gm * KK + 0];
    if (v0 == 0.0f) { allLq[b] = 1; return; }        // all-zero row: all lq
    unsigned char* fl = lqflag + (size_t)b * NN;
    fl[topi[gm * KK + 0]] = 1;
    const float v1 = topv[gm * KK + 1], v2 = topv[gm * KK + 2], v3 = topv[gm * KK + 3];
    if (v1 == v0) fl[topi[gm * KK + 1]] = 1;
    if (v2 == v0) fl[topi[gm * KK + 2]] = 1;
    if (v3 == v0) {
        fl[topi[gm * KK + 3]] = 1;
        // >=4 achievers possible beyond top-4: exact serial row rescan.
        float4 gg = ((const float4*)(gt + (size_t)b * MM * 4))[m];
        float x1 = gg.x - 0.5f * gg.z, y1 = gg.y - 0.5f * gg.w;
        float x2 = gg.x + 0.5f * gg.z, y2 = gg.y + 0.5f * gg.w;
        float ga = __fmul_rn(x2 - x1, y2 - y1);
        const float4* p4 = (const float4*)(pr + (size_t)b * NN * 4);
        for (int n = 0; n < NN; ++n) {
            float4 qc = p4[n];
            float px1 = qc.x - 0.5f * qc.z, py1 = qc.y - 0.5f * qc.w;
            float px2 = qc.x + 0.5f * qc.z, py2 = qc.y + 0.5f * qc.w;
            float pa = __fmul_rn(px2 - px1, py2 - py1);
            float ltx = fmaxf(x1, px1), lty = fmaxf(y1, py1);
            float rbx = fminf(x2, px2), rby = fminf(y2, py2);
            float w = fmaxf(rbx - ltx, 0.0f), h = fmaxf(rby - lty, 0.0f);
            float IN = __fmul_rn(w, h);
            float u = fmaxf((ga + pa) - IN, 1e-9f);
            if ((IN / u) == v0) fl[n] = 1;
        }
    }
}

// ---------------------------------------------------------------------------
// Kernel E: per-proposal count scatter: pos = fg | lqflag | allLq.
// ---------------------------------------------------------------------------
__global__ __launch_bounds__(256) void kernE(const int* __restrict__ bestv,
                                             const int* __restrict__ bidxA,
                                             const unsigned char* __restrict__ lqflag,
                                             const int* __restrict__ allLq,
                                             int* __restrict__ counts) {
    const int idx = blockIdx.x * 256 + threadIdx.x;  // 0 .. B*N-1
    const int b = idx >> 12;
    const int bb = bestv[idx];
    const int mi = bidxA[idx];
    const bool pos = (bb >= FG_BITS) || lqflag[idx] || (allLq[b] != 0);
    if (pos) atomicAdd(&counts[b * MM + mi], 1);
}

// ---------------------------------------------------------------------------
// Kernel C: write scores + valid sections (pr_inds/gt_inds done by A-role).
// ---------------------------------------------------------------------------
__global__ __launch_bounds__(256) void kernC(const float* __restrict__ topv,
                                             const int* __restrict__ counts,
                                             float* __restrict__ out) {
    const int gm = blockIdx.x * 256 + threadIdx.x;   // 0 .. B*M-1
    if (gm >= BB * MM) return;
    const int cnt = counts[gm];
    float* sc = out;
    float* va = out + (size_t)3 * BB * MM * KK;
    #pragma unroll
    for (int k = 0; k < KK; ++k) {
        const bool val = k < cnt;
        sc[gm * KK + k] = val ? topv[gm * KK + k] : 0.0f;
        va[gm * KK + k] = val ? 1.0f : 0.0f;
    }
}

extern "C" void kernel_launch(void* const* d_in, const int* in_sizes, int n_in,
                              void* d_out, int out_size, void* d_ws, size_t ws_size,
                              hipStream_t stream) {
    const float* gt = (const float*)d_in[0];   // [B,M,4] cxcywh
    const float* pr = (const float*)d_in[1];   // [B,N,4] cxcywh
    // d_in[2] (gt_labels) is unused by the reference outputs.
    float* out = (float*)d_out;
    char* ws = (char*)d_ws;

    int*           counts = (int*)(ws);                         //  64 KB @ 0
    float*         topv   = (float*)(ws + (1 << 16));           // 256 KB @ 64K
    int*           topi   = (int*)(ws + (5 << 16));             // 256 KB @ 320K
    int*           bestv  = (int*)(ws + (9 << 16));             // 512 KB @ 576K
    int*           bidxA  = (int*)(ws + (17 << 16));            // 512 KB @ 1088K
    unsigned char* lqflag = (unsigned char*)(ws + (25 << 16));  // 128 KB @ 1600K
    int*           allLq  = (int*)(ws + (27 << 16));            // 128 B  @ 1728K

    kernAB<<<2 * NA_BLOCKS, 256, 0, stream>>>(gt, pr, topv, topi, counts,
                                              bestv, bidxA, lqflag, allLq, out);
    kernD<<<(BB * MM + 255) / 256, 256, 0, stream>>>(topv, topi, gt, pr, lqflag, allLq);
    kernE<<<(BB * NN) / 256, 256, 0, stream>>>(bestv, bidxA, lqflag, allLq, counts);
    kernC<<<(BB * MM + 255) / 256, 256, 0, stream>>>(topv, counts, out);
}

// Round 18
// 89.785 us; speedup vs baseline: 1.4187x; 1.0554x over previous
//
#include <hip/hip_runtime.h>

#define BB 32
#define MM 512
#define NN 4096
#define KK 4
#define MLO 0.999998f         // 1 - 2^-19: kernA trigger margin, no false negatives
#define CMG 0.9999995f        // 1 - 2^-21: close margin, dominates all roundings
#define FG_BITS 0x3F19999A    // bit pattern of 0.6f
#define NA_BLOCKS (BB * (MM / 16))  // 1024 A-role blocks (16 gts each)
#define NB_BLOCKS (BB * (NN / 64))  // 2048 B-role blocks

// All IoU values are >= +0.0f, so float ordering == signed-int ordering on the
// bit patterns, with -1 (int) as a below-everything sentinel.

__device__ __forceinline__ int rfl(int x) {
    return __builtin_amdgcn_readfirstlane(x);
}
__device__ __forceinline__ float rflf(float x) {
    return __int_as_float(rfl(__float_as_int(x)));
}

__device__ __forceinline__ bool beatsI(int v1, int i1, int v2, int i2) {
    return (v1 > v2) || (v1 == v2 && i1 < i2);
}

#define CE(av, ai, bv, bi)                                        \
    {                                                             \
        bool _s = beatsI(bv, bi, av, ai);                         \
        int _mv = _s ? bv : av, _nv = _s ? av : bv;               \
        int _mi = _s ? bi : ai, _ni = _s ? ai : bi;               \
        av = _mv; bv = _nv; ai = _mi; bi = _ni;                   \
    }

struct T4 { int v0, v1, v2, v3; int i0, i1, i2, i3; float thr, c1, thrga; };

// ---------------------------------------------------------------------------
// Fused kernel. Blocks [0, 1024): A-role, now 4 gts/WAVE (16/block) -- the
// per-iteration shared work (proposal load+convert+pa+ballot+branch ~12-14
// slots) amortizes over 4 gts instead of 2 (r17 A-side ~19 slots/64-pairs ->
// ~15.5). SGPR top-4 state x4 (~88 SGPRs, fits). Blocks [1024, 3072):
// B-role, VERBATIM r17 (validated, absmax 0): per-proposal argmax via
// cross-mult fraction state + close detector, no div in loop, no lq.
// ---------------------------------------------------------------------------
__global__ __launch_bounds__(256) void kernAB(const float* __restrict__ gt,
                                              const float* __restrict__ pr,
                                              float* __restrict__ topv,
                                              int* __restrict__ topi,
                                              int* __restrict__ counts,
                                              int* __restrict__ bestv,
                                              int* __restrict__ bidxA,
                                              unsigned char* __restrict__ lqflag,
                                              int* __restrict__ allLq,
                                              float* __restrict__ out) {
    __shared__ float4 sG[MM];              // B-role: xyxy, 8 KB
    __shared__ float sAr[MM];              // B-role: area, 2 KB
    __shared__ int sV[256], sI[256];       // B-role reduce, 2 KB

    if (blockIdx.x < NA_BLOCKS) {
        // =================== A-role: per-gt top-4, 4 gts/wave ===================
        const int b = blockIdx.x >> 5;     // 32 blocks per batch (512 gts / 16)
        const int mblk = blockIdx.x & 31;
        const int tid = threadIdx.x;
        const int wave = rfl(tid >> 6), lane = tid & 63;
        const int mbase = mblk * 16 + wave * 4;
        const float4* g4 = (const float4*)(gt + (size_t)b * MM * 4);
        const float4* p4 = (const float4*)(pr + (size_t)b * NN * 4);

#define GTDEF(G) \
    float gx1_##G, gy1_##G, gx2_##G, gy2_##G, ga_##G; \
    { float4 gg = g4[mbase + G]; \
      float x1 = gg.x - 0.5f * gg.z, y1 = gg.y - 0.5f * gg.w; \
      float x2 = gg.x + 0.5f * gg.z, y2 = gg.y + 0.5f * gg.w; \
      gx1_##G = x1; gy1_##G = y1; gx2_##G = x2; gy2_##G = y2; \
      ga_##G = __fmul_rn(x2 - x1, y2 - y1); }

        GTDEF(0) GTDEF(1) GTDEF(2) GTDEF(3)

        T4 t0, t1, t2, t3;

#define PIOU(G, VB) \
    int VB; \
    { float ltx = fmaxf(gx1_##G, px1), lty = fmaxf(gy1_##G, py1); \
      float rbx = fminf(gx2_##G, px2), rby = fminf(gy2_##G, py2); \
      float wc = fmaxf(rbx - ltx, 0.0f), hc = fmaxf(rby - lty, 0.0f); \
      float inter = __fmul_rn(wc, hc); \
      float u = fmaxf((ga_##G + pa) - inter, 1e-9f); \
      VB = __float_as_int(inter / u); }

#define PRIME(T, VB, G) \
    { int x0 = VB, x1 = -1, x2 = -1, x3 = -1; \
      int y0 = lane, y1 = 0x7fffffff, y2 = 0x7fffffff, y3 = 0x7fffffff; \
      for (int off = 1; off < 64; off <<= 1) { \
        int b0 = __shfl_xor(x0, off), b1 = __shfl_xor(x1, off); \
        int b2 = __shfl_xor(x2, off), b3 = __shfl_xor(x3, off); \
        int j0 = __shfl_xor(y0, off), j1 = __shfl_xor(y1, off); \
        int j2 = __shfl_xor(y2, off), j3 = __shfl_xor(y3, off); \
        int z4 = b3, z5 = b2, z6 = b1, z7 = b0; \
        int w4 = j3, w5 = j2, w6 = j1, w7 = j0; \
        CE(x0, y0, z4, w4); CE(x1, y1, z5, w5); \
        CE(x2, y2, z6, w6); CE(x3, y3, z7, w7); \
        CE(x0, y0, x2, y2); CE(x1, y1, x3, y3); \
        CE(x0, y0, x1, y1); CE(x2, y2, x3, y3); \
      } \
      T.v0 = rfl(x0); T.v1 = rfl(x1); T.v2 = rfl(x2); T.v3 = rfl(x3); \
      T.i0 = rfl(y0); T.i1 = rfl(y1); T.i2 = rfl(y2); T.i3 = rfl(y3); \
      T.thr = (T.v3 <= 0) ? 0.0f : rflf(__int_as_float(T.v3) * MLO); \
      T.c1 = 1.0f + T.thr; T.thrga = T.thr * ga_##G; }

        {
            float4 qc = p4[lane];
            float px1 = qc.x - 0.5f * qc.z, py1 = qc.y - 0.5f * qc.w;
            float px2 = qc.x + 0.5f * qc.z, py2 = qc.y + 0.5f * qc.w;
            float pa = __fmul_rn(px2 - px1, py2 - py1);
            PIOU(0, vb0) PIOU(1, vb1) PIOU(2, vb2) PIOU(3, vb3)
            PRIME(t0, vb0, 0) PRIME(t1, vb1, 1) PRIME(t2, vb2, 2) PRIME(t3, vb3, 3)
        }

#define COMP(T, G, IN, TR) \
    float IN; bool TR; \
    { float ltx = fmaxf(gx1_##G, px1), lty = fmaxf(gy1_##G, py1); \
      float rbx = fminf(gx2_##G, px2), rby = fminf(gy2_##G, py2); \
      float wc = fmaxf(rbx - ltx, 0.0f), hc = fmaxf(rby - lty, 0.0f); \
      IN = __fmul_rn(wc, hc); \
      TR = IN * T.c1 > __fmaf_rn(T.thr, pa, T.thrga); }

#define MERGE(T, G, MK, IN, TR) \
    if (MK) { \
      float iouv = 0.0f; \
      if (TR) { float uu = fmaxf((ga_##G + pa) - IN, 1e-9f); iouv = IN / uu; } \
      unsigned long long mk = MK; \
      do { \
        int l = __ffsll((unsigned long long)mk) - 1; mk &= mk - 1; \
        int vb = (int)__builtin_amdgcn_readlane(__float_as_int(iouv), l); \
        if (vb > T.v3) { \
          int n = nb + l; \
          bool c2 = vb > T.v2, c1c = vb > T.v1, c0 = vb > T.v0; \
          T.v3 = c2 ? T.v2 : vb;                T.i3 = c2 ? T.i2 : n; \
          T.v2 = c2 ? (c1c ? T.v1 : vb) : T.v2; T.i2 = c2 ? (c1c ? T.i1 : n) : T.i2; \
          T.v1 = c1c ? (c0 ? T.v0 : vb) : T.v1; T.i1 = c1c ? (c0 ? T.i0 : n) : T.i1; \
          T.v0 = c0 ? vb : T.v0;                T.i0 = c0 ? n : T.i0; \
        } \
      } while (mk); \
      T.thr = (T.v3 == 0) ? 0.0f : rflf(__int_as_float(T.v3) * MLO); \
      T.c1 = 1.0f + T.thr; T.thrga = T.thr * ga_##G; \
    }

        float4 qn = p4[64 + lane];
        for (int j = 1; j < 64; ++j) {
            float4 qc = qn;
            int jn = (j < 63) ? j + 1 : 63;
            qn = p4[jn * 64 + lane];       // prefetch next tile (L2-resident)
            float px1 = qc.x - 0.5f * qc.z, py1 = qc.y - 0.5f * qc.w;
            float px2 = qc.x + 0.5f * qc.z, py2 = qc.y + 0.5f * qc.w;
            float pa = __fmul_rn(px2 - px1, py2 - py1);
            const int nb = j * 64;
            COMP(t0, 0, in0, tr0)
            COMP(t1, 1, in1, tr1)
            COMP(t2, 2, in2, tr2)
            COMP(t3, 3, in3, tr3)
            unsigned long long mk0 = __ballot(tr0), mk1 = __ballot(tr1);
            unsigned long long mk2 = __ballot(tr2), mk3 = __ballot(tr3);
            if ((mk0 | mk1) | (mk2 | mk3)) {
                MERGE(t0, 0, mk0, in0, tr0)
                MERGE(t1, 1, mk1, in1, tr1)
                MERGE(t2, 2, mk2, in2, tr2)
                MERGE(t3, 3, mk3, in3, tr3)
            }
        }

        if (lane == 0) {
            float* pi = out + (size_t)BB * MM * KK;
            float* gi = out + (size_t)2 * BB * MM * KK;
#define WOUT(T, G) \
            { int gm = b * MM + mbase + G; \
              topv[gm * KK + 0] = __int_as_float(T.v0); \
              topv[gm * KK + 1] = __int_as_float(T.v1); \
              topv[gm * KK + 2] = __int_as_float(T.v2); \
              topv[gm * KK + 3] = __int_as_float(T.v3); \
              topi[gm * KK + 0] = T.i0; topi[gm * KK + 1] = T.i1; \
              topi[gm * KK + 2] = T.i2; topi[gm * KK + 3] = T.i3; \
              pi[gm * KK + 0] = (float)T.i0; pi[gm * KK + 1] = (float)T.i1; \
              pi[gm * KK + 2] = (float)T.i2; pi[gm * KK + 3] = (float)T.i3; \
              float fm = (float)(mbase + G); \
              gi[gm * KK + 0] = fm; gi[gm * KK + 1] = fm; \
              gi[gm * KK + 2] = fm; gi[gm * KK + 3] = fm; \
              counts[gm] = 0; }
            WOUT(t0, 0) WOUT(t1, 1) WOUT(t2, 2) WOUT(t3, 3)
        }
    } else {
        // =================== B-role (r17 verbatim) ===================
        const int bid = blockIdx.x - NA_BLOCKS;
        const int b = bid >> 6;            // 64 blocks per batch (4096/64)
        const int nblk = bid & 63;
        const int tid = threadIdx.x;
        const float4* g4 = (const float4*)(gt + (size_t)b * MM * 4);

        for (int i = tid; i < MM; i += 256) {
            float4 gg = g4[i];
            float x1 = gg.x - 0.5f * gg.z, y1 = gg.y - 0.5f * gg.w;
            float x2 = gg.x + 0.5f * gg.z, y2 = gg.y + 0.5f * gg.w;
            sG[i] = make_float4(x1, y1, x2, y2);
            sAr[i] = __fmul_rn(x2 - x1, y2 - y1);
        }
        if (tid < 64) lqflag[(size_t)b * NN + nblk * 64 + tid] = 0;
        if (tid == 0 && nblk == 0) allLq[b] = 0;

        const int lane = tid & 63;
        const int qtr = tid >> 6;
        const int m0 = qtr * 128;
        const int n = nblk * 64 + lane;
        float4 qq = ((const float4*)(pr + (size_t)b * NN * 4))[n];
        const float qx1 = qq.x - 0.5f * qq.z, qy1 = qq.y - 0.5f * qq.w;
        const float qx2 = qq.x + 0.5f * qq.z, qy2 = qq.y + 0.5f * qq.w;
        const float pa = __fmul_rn(qx2 - qx1, qy2 - qy1);
        __syncthreads();

        float INb = 0.0f, ub = 1.0f;
        int mb = m0;
        bool closeacc = false;

        #pragma unroll 4
        for (int mm = 0; mm < 128; ++mm) {
            const int m = m0 + mm;
            float4 gb = sG[m];
            float ar = sAr[m];
            float ltx = fmaxf(gb.x, qx1), lty = fmaxf(gb.y, qy1);
            float rbx = fminf(gb.z, qx2), rby = fminf(gb.w, qy2);
            float w = fmaxf(rbx - ltx, 0.0f), h = fmaxf(rby - lty, 0.0f);
            float IN = __fmul_rn(w, h);
            float u = fmaxf((ar + pa) - IN, 1e-9f);
            float t1 = __fmul_rn(IN, ub);
            float t2 = __fmul_rn(INb, u);
            bool c = t1 > t2;
            closeacc = closeacc || ((t1 > t2 * CMG) && (t2 > t1 * CMG));
            INb = c ? IN : INb;
            ub = c ? u : ub;
            mb = c ? m : mb;
        }

        float bestE;
        {
            float4 gb = sG[mb];
            float ltx = fmaxf(gb.x, qx1), lty = fmaxf(gb.y, qy1);
            float rbx = fminf(gb.z, qx2), rby = fminf(gb.w, qy2);
            float w = fmaxf(rbx - ltx, 0.0f), h = fmaxf(rby - lty, 0.0f);
            float IN = __fmul_rn(w, h);
            float u = fmaxf((sAr[mb] + pa) - IN, 1e-9f);
            bestE = IN / u;
        }
        if (__ballot(closeacc) != 0ull) {
            if (closeacc) {
                float bb = 0.0f; int bi = m0;
                for (int mm = 0; mm < 128; ++mm) {
                    const int m = m0 + mm;
                    float4 gb = sG[m];
                    float ltx = fmaxf(gb.x, qx1), lty = fmaxf(gb.y, qy1);
                    float rbx = fminf(gb.z, qx2), rby = fminf(gb.w, qy2);
                    float w = fmaxf(rbx - ltx, 0.0f), h = fmaxf(rby - lty, 0.0f);
                    float IN = __fmul_rn(w, h);
                    float u = fmaxf((sAr[m] + pa) - IN, 1e-9f);
                    float iou = IN / u;
                    bool c = iou > bb;
                    bb = c ? iou : bb;
                    bi = c ? m : bi;
                }
                bestE = bb; mb = bi;
            }
        }

        sV[tid] = __float_as_int(bestE);
        sI[tid] = mb;
        __syncthreads();

        if (tid < 64) {
            int v = sV[tid], i = sI[tid];
            #pragma unroll
            for (int q_ = 1; q_ < 4; ++q_) {
                int v2 = sV[tid + q_ * 64], i2 = sI[tid + q_ * 64];
                bool c = v2 > v;
                v = c ? v2 : v;
                i = c ? i2 : i;
            }
            const size_t pidx = (size_t)b * NN + nblk * 64 + tid;
            bestv[pidx] = v;
            bidxA[pidx] = i;
        }
    }
}

// ---------------------------------------------------------------------------
// Kernel D: per-gt lq marking from top-4 ties (exact, no epsilon).
// ---------------------------------------------------------------------------
__global__ __launch_bounds__(256) void kernD(const float* __restrict__ topv,
                                             const int* __restrict__ topi,
                                             const float* __restrict__ gt,
                                             const float* __restrict__ pr,
                                             unsigned char* __restrict__ lqflag,
                                             int* __restrict__ allLq) {
    const int gm = blockIdx.x * 256 + threadIdx.x;   // 0 .. B*M-1
    if (gm >= BB * MM) return;
    const int b = gm >> 9, m = gm & (MM - 1);
    const float v0 = topv[gm * KK + 0];
    if (v0 == 0.0f) { allLq[b] = 1; return; }        // all-zero row: all lq
    unsigned char* fl = lqflag + (size_t)b * NN;
    fl[topi[gm * KK + 0]] = 1;
    const float v1 = topv[gm * KK + 1], v2 = topv[gm * KK + 2], v3 = topv[gm * KK + 3];
    if (v1 == v0) fl[topi[gm * KK + 1]] = 1;
    if (v2 == v0) fl[topi[gm * KK + 2]] = 1;
    if (v3 == v0) {
        fl[topi[gm * KK + 3]] = 1;
        // >=4 achievers possible beyond top-4: exact serial row rescan.
        float4 gg = ((const float4*)(gt + (size_t)b * MM * 4))[m];
        float x1 = gg.x - 0.5f * gg.z, y1 = gg.y - 0.5f * gg.w;
        float x2 = gg.x + 0.5f * gg.z, y2 = gg.y + 0.5f * gg.w;
        float ga = __fmul_rn(x2 - x1, y2 - y1);
        const float4* p4 = (const float4*)(pr + (size_t)b * NN * 4);
        for (int n = 0; n < NN; ++n) {
            float4 qc = p4[n];
            float px1 = qc.x - 0.5f * qc.z, py1 = qc.y - 0.5f * qc.w;
            float px2 = qc.x + 0.5f * qc.z, py2 = qc.y + 0.5f * qc.w;
            float pa = __fmul_rn(px2 - px1, py2 - py1);
            float ltx = fmaxf(x1, px1), lty = fmaxf(y1, py1);
            float rbx = fminf(x2, px2), rby = fminf(y2, py2);
            float w = fmaxf(rbx - ltx, 0.0f), h = fmaxf(rby - lty, 0.0f);
            float IN = __fmul_rn(w, h);
            float u = fmaxf((ga + pa) - IN, 1e-9f);
            if ((IN / u) == v0) fl[n] = 1;
        }
    }
}

// ---------------------------------------------------------------------------
// Kernel E: per-proposal count scatter: pos = fg | lqflag | allLq.
// ---------------------------------------------------------------------------
__global__ __launch_bounds__(256) void kernE(const int* __restrict__ bestv,
                                             const int* __restrict__ bidxA,
                                             const unsigned char* __restrict__ lqflag,
                                             const int* __restrict__ allLq,
                                             int* __restrict__ counts) {
    const int idx = blockIdx.x * 256 + threadIdx.x;  // 0 .. B*N-1
    const int b = idx >> 12;
    const int bb = bestv[idx];
    const int mi = bidxA[idx];
    const bool pos = (bb >= FG_BITS) || lqflag[idx] || (allLq[b] != 0);
    if (pos) atomicAdd(&counts[b * MM + mi], 1);
}

// ---------------------------------------------------------------------------
// Kernel C: write scores + valid sections (pr_inds/gt_inds done by A-role).
// ---------------------------------------------------------------------------
__global__ __launch_bounds__(256) void kernC(const float* __restrict__ topv,
                                             const int* __restrict__ counts,
                                             float* __restrict__ out) {
    const int gm = blockIdx.x * 256 + threadIdx.x;   // 0 .. B*M-1
    if (gm >= BB * MM) return;
    const int cnt = counts[gm];
    float* sc = out;
    float* va = out + (size_t)3 * BB * MM * KK;
    #pragma unroll
    for (int k = 0; k < KK; ++k) {
        const bool val = k < cnt;
        sc[gm * KK + k] = val ? topv[gm * KK + k] : 0.0f;
        va[gm * KK + k] = val ? 1.0f : 0.0f;
    }
}

extern "C" void kernel_launch(void* const* d_in, const int* in_sizes, int n_in,
                              void* d_out, int out_size, void* d_ws, size_t ws_size,
                              hipStream_t stream) {
    const float* gt = (const float*)d_in[0];   // [B,M,4] cxcywh
    const float* pr = (const float*)d_in[1];   // [B,N,4] cxcywh
    // d_in[2] (gt_labels) is unused by the reference outputs.
    float* out = (float*)d_out;
    char* ws = (char*)d_ws;

    int*           counts = (int*)(ws);                         //  64 KB @ 0
    float*         topv   = (float*)(ws + (1 << 16));           // 256 KB @ 64K
    int*           topi   = (int*)(ws + (5 << 16));             // 256 KB @ 320K
    int*           bestv  = (int*)(ws + (9 << 16));             // 512 KB @ 576K
    int*           bidxA  = (int*)(ws + (17 << 16));            // 512 KB @ 1088K
    unsigned char* lqflag = (unsigned char*)(ws + (25 << 16));  // 128 KB @ 1600K
    int*           allLq  = (int*)(ws + (27 << 16));            // 128 B  @ 1728K

    kernAB<<<NA_BLOCKS + NB_BLOCKS, 256, 0, stream>>>(gt, pr, topv, topi, counts,
                                                      bestv, bidxA, lqflag, allLq, out);
    kernD<<<(BB * MM + 255) / 256, 256, 0, stream>>>(topv, topi, gt, pr, lqflag, allLq);
    kernE<<<(BB * NN) / 256, 256, 0, stream>>>(bestv, bidxA, lqflag, allLq, counts);
    kernC<<<(BB * MM + 255) / 256, 256, 0, stream>>>(topv, counts, out);
}